// Round 1
// baseline (67.176 us; speedup 1.0000x reference)
//
#include <hip/hip_runtime.h>
#include <hip/hip_bf16.h>
#include <stdint.h>

#define B_ 8
#define N_ 2048
#define F_ 128
#define D_ 128

typedef short bf16x8 __attribute__((ext_vector_type(8)));
typedef float f32x4 __attribute__((ext_vector_type(4)));

// round-to-nearest-even fp32 -> bf16
__device__ __forceinline__ unsigned short f2bf(float f) {
    unsigned u = __float_as_uint(f);
    u += 0x7fffu + ((u >> 16) & 1u);
    return (unsigned short)(u >> 16);
}

// ---------------- Kernel 1: degrees -> rsqrt ----------------
// one wave per row of adj; 4 rows per 256-thread block
__global__ __launch_bounds__(256) void k_deg(const float* __restrict__ adj,
                                             float* __restrict__ rs) {
    const int wave = threadIdx.x >> 6, lane = threadIdx.x & 63;
    const int row = blockIdx.x * 4 + wave;          // 0..B_*N_-1
    const float4* p = (const float4*)(adj + (size_t)row * N_);
    float s = 0.f;
#pragma unroll
    for (int j = 0; j < 8; ++j) {
        float4 v = p[j * 64 + lane];
        s += (v.x + v.y) + (v.z + v.w);
    }
#pragma unroll
    for (int m = 1; m < 64; m <<= 1) s += __shfl_xor(s, m, 64);
    if (lane == 0) rs[row] = (s > 0.f) ? (1.0f / sqrtf(s)) : 0.f;
}

// ---------------- Kernel 2: gt[b][d][m] = rsqrt_d[m]*(X@W + bias), bf16 ----------------
// block: 64 rows (m) x 128 cols (d), 4 waves, MFMA 16x16x32 bf16
__global__ __launch_bounds__(256) void k_feat(const float* __restrict__ x,
                                              const float* __restrict__ W,
                                              const float* __restrict__ bias,
                                              const float* __restrict__ rs,
                                              unsigned short* __restrict__ gt) {
    __shared__ __align__(16) unsigned char sX[64 * 128 * 2];   // [row][f] bf16, 256B rows, swizzled
    __shared__ __align__(16) unsigned char sW[128 * 128 * 2];  // [d][f] bf16 (W^T), swizzled
    const int t = threadIdx.x;
    const int R0 = blockIdx.x * 64;

    // stage X: 1024 x 16B chunks (8 bf16 each), 4 per thread
#pragma unroll
    for (int j = 0; j < 4; ++j) {
        int c = j * 256 + t;
        int row = c >> 4, sub = c & 15;
        const float4* src = (const float4*)(x + (size_t)(R0 + row) * F_ + sub * 8);
        float4 v0 = src[0], v1 = src[1];
        union { bf16x8 v; unsigned short u[8]; } pk;
        pk.u[0] = f2bf(v0.x); pk.u[1] = f2bf(v0.y); pk.u[2] = f2bf(v0.z); pk.u[3] = f2bf(v0.w);
        pk.u[4] = f2bf(v1.x); pk.u[5] = f2bf(v1.y); pk.u[6] = f2bf(v1.z); pk.u[7] = f2bf(v1.w);
        unsigned byte = (unsigned)(row * 256 + sub * 16);
        byte ^= ((byte >> 8) & 7u) << 4;
        *(bf16x8*)(sX + byte) = pk.v;
    }
    // stage W^T: 2048 x 16B chunks, 8 per thread (scattered reads, L2-hit)
#pragma unroll
    for (int j = 0; j < 8; ++j) {
        int c = j * 256 + t;
        int d = c >> 4, sub = c & 15;
        union { bf16x8 v; unsigned short u[8]; } pk;
#pragma unroll
        for (int e = 0; e < 8; ++e) pk.u[e] = f2bf(W[(size_t)(sub * 8 + e) * D_ + d]);
        unsigned byte = (unsigned)(d * 256 + sub * 16);
        byte ^= ((byte >> 8) & 7u) << 4;
        *(bf16x8*)(sW + byte) = pk.v;
    }
    __syncthreads();

    const int w = t >> 6, l = t & 63, lr = l & 15, lh = l >> 4;
    f32x4 acc[8];
#pragma unroll
    for (int j = 0; j < 8; ++j) acc[j] = (f32x4){0.f, 0.f, 0.f, 0.f};

#pragma unroll
    for (int ks = 0; ks < 4; ++ks) {
        int f0 = lh * 8 + ks * 32;
        unsigned abyte = (unsigned)((w * 16 + lr) * 256 + f0 * 2);
        abyte ^= ((abyte >> 8) & 7u) << 4;
        bf16x8 a = *(const bf16x8*)(sX + abyte);
#pragma unroll
        for (int j = 0; j < 8; ++j) {
            unsigned bbyte = (unsigned)((j * 16 + lr) * 256 + f0 * 2);
            bbyte ^= ((bbyte >> 8) & 7u) << 4;
            bf16x8 bb = *(const bf16x8*)(sW + bbyte);
            acc[j] = __builtin_amdgcn_mfma_f32_16x16x32_bf16(a, bb, acc[j], 0, 0, 0);
        }
    }

    // epilogue: add bias, scale by rsqrt_d[m], store transposed bf16
#pragma unroll
    for (int j = 0; j < 8; ++j) {
        int d = j * 16 + lr;
        float bv = bias[d];
#pragma unroll
        for (int r = 0; r < 4; ++r) {
            int m = R0 + w * 16 + lh * 4 + r;
            float v = (acc[j][r] + bv) * rs[m];
            int b = m >> 11, n = m & (N_ - 1);
            gt[((size_t)b * D_ + d) * N_ + n] = f2bf(v);
        }
    }
}

// ---------------- Kernel 3: out = relu(rs[n] * adj @ gt^T) ----------------
// block: 32 rows(n) x 128 cols(d), K=2048 over m. 4 waves, each 32x32.
__global__ __launch_bounds__(256) void k_gcn(const float* __restrict__ adj,
                                             const unsigned short* __restrict__ gt,
                                             const float* __restrict__ rs,
                                             float* __restrict__ out) {
    __shared__ __align__(16) unsigned char sA[2][32 * 64 * 2];    // adj tile bf16, 128B rows, swz
    __shared__ __align__(16) unsigned char sB[2][128 * 64 * 2];   // gt tile [d][m] bf16, swz

    // XCD-aware swizzle: 512 blocks, 8 XCDs -> each XCD owns one batch
    unsigned bid = blockIdx.x;
    unsigned wg = (bid & 7u) * 64u + (bid >> 3);
    const int b = (int)(wg >> 6);
    const int nt = (int)(wg & 63u);
    const int R0 = nt * 32;

    const float* adjB = adj + (size_t)b * N_ * N_ + (size_t)R0 * N_;
    const unsigned short* gtB = gt + (size_t)b * D_ * N_;

    const int t = threadIdx.x;
    const int w = t >> 6, l = t & 63, lr = l & 15, lh = l >> 4;

    auto stage = [&](int bufidx, int k0) {
        // B: gt[d][k0..k0+63] -> sB, 1024 x 16B chunks via global_load_lds,
        // linear LDS dest + inverse-swizzled global source (both-sides rule)
        unsigned char* sBb = sB[bufidx];
#pragma unroll
        for (int i = 0; i < 4; ++i) {
            int c = i * 256 + t;
            int d = c >> 3, sub = c & 7;
            int sub2 = sub ^ (d & 7);
            const unsigned short* g = gtB + (size_t)d * N_ + k0 + sub2 * 8;
            __builtin_amdgcn_global_load_lds(
                (const __attribute__((address_space(1))) void*)g,
                (__attribute__((address_space(3))) void*)(sBb + c * 16), 16, 0, 0);
        }
        // A: adj fp32 -> bf16 reg-staged, 256 x 16B chunks, 1 per thread
        {
            int c = t;
            int row = c >> 3, sub = c & 7;
            const float4* src = (const float4*)(adjB + (size_t)row * N_ + k0 + sub * 8);
            float4 v0 = src[0], v1 = src[1];
            union { bf16x8 v; unsigned short u[8]; } pk;
            pk.u[0] = f2bf(v0.x); pk.u[1] = f2bf(v0.y); pk.u[2] = f2bf(v0.z); pk.u[3] = f2bf(v0.w);
            pk.u[4] = f2bf(v1.x); pk.u[5] = f2bf(v1.y); pk.u[6] = f2bf(v1.z); pk.u[7] = f2bf(v1.w);
            unsigned byte = (unsigned)(row * 128 + sub * 16);
            byte ^= ((byte >> 7) & 7u) << 4;
            *(bf16x8*)(sA[bufidx] + byte) = pk.v;
        }
    };

    f32x4 acc[2][2];
#pragma unroll
    for (int i = 0; i < 2; ++i)
#pragma unroll
        for (int jn = 0; jn < 2; ++jn) acc[i][jn] = (f32x4){0.f, 0.f, 0.f, 0.f};

    stage(0, 0);
    __syncthreads();

    const int NITER = N_ / 64;  // 32
    for (int it = 0; it < NITER; ++it) {
        int cur = it & 1;
        if (it + 1 < NITER) stage(cur ^ 1, (it + 1) * 64);

        const unsigned char* pA = sA[cur];
        const unsigned char* pB = sB[cur];
#pragma unroll
        for (int kk = 0; kk < 2; ++kk) {
            bf16x8 a[2], bb[2];
#pragma unroll
            for (int i = 0; i < 2; ++i) {
                unsigned byte = (unsigned)((i * 16 + lr) * 128 + lh * 16 + kk * 64);
                byte ^= ((byte >> 7) & 7u) << 4;
                a[i] = *(const bf16x8*)(pA + byte);
            }
#pragma unroll
            for (int jn = 0; jn < 2; ++jn) {
                int d = w * 32 + jn * 16 + lr;
                unsigned byte = (unsigned)(d * 128 + lh * 16 + kk * 64);
                byte ^= ((byte >> 7) & 7u) << 4;
                bb[jn] = *(const bf16x8*)(pB + byte);
            }
#pragma unroll
            for (int i = 0; i < 2; ++i)
#pragma unroll
                for (int jn = 0; jn < 2; ++jn)
                    acc[i][jn] = __builtin_amdgcn_mfma_f32_16x16x32_bf16(a[i], bb[jn], acc[i][jn], 0, 0, 0);
        }
        __syncthreads();
    }

    // epilogue: scale by rs[n], relu, store fp32
#pragma unroll
    for (int i = 0; i < 2; ++i) {
#pragma unroll
        for (int r = 0; r < 4; ++r) {
            int row = i * 16 + lh * 4 + r;
            float rsn = rs[b * N_ + R0 + row];
#pragma unroll
            for (int jn = 0; jn < 2; ++jn) {
                int d = w * 32 + jn * 16 + lr;
                float v = acc[i][jn][r] * rsn;
                out[((size_t)(b * N_ + R0 + row)) * D_ + d] = fmaxf(v, 0.f);
            }
        }
    }
}

extern "C" void kernel_launch(void* const* d_in, const int* in_sizes, int n_in,
                              void* d_out, int out_size, void* d_ws, size_t ws_size,
                              hipStream_t stream) {
    const float* inputs = (const float*)d_in[0];   // [B,N,F]
    const float* adj    = (const float*)d_in[1];   // [B,N,N]
    const float* Wk     = (const float*)d_in[2];   // [F,D]
    const float* Wb     = (const float*)d_in[3];   // [D]
    float* out = (float*)d_out;

    float* rs = (float*)d_ws;                                   // B*N fp32 = 64KB
    unsigned short* gt = (unsigned short*)((char*)d_ws + 65536); // B*D*N bf16 = 4MB

    k_deg <<<(B_ * N_) / 4, 256, 0, stream>>>(adj, rs);
    k_feat<<<(B_ * N_) / 64, 256, 0, stream>>>(inputs, Wk, Wb, rs, gt);
    k_gcn <<<B_ * (N_ / 32), 256, 0, stream>>>(adj, gt, rs, out);
}

// Round 2
// 56.735 us; speedup vs baseline: 1.1840x; 1.1840x over previous
//
#include <hip/hip_runtime.h>
#include <hip/hip_bf16.h>
#include <stdint.h>

#define B_ 8
#define N_ 2048
#define F_ 128
#define D_ 128

typedef short bf16x8 __attribute__((ext_vector_type(8)));
typedef float f32x4 __attribute__((ext_vector_type(4)));

// round-to-nearest-even fp32 -> bf16
__device__ __forceinline__ unsigned short f2bf(float f) {
    unsigned u = __float_as_uint(f);
    u += 0x7fffu + ((u >> 16) & 1u);
    return (unsigned short)(u >> 16);
}

// ---------------- Kernel 1: degrees -> rsqrt  (+ W transpose in tail blocks) ----------------
// blocks 0..4095: one wave per adj row (4 rows/block)
// blocks 4096..4103: transpose W[f][d] fp32 -> Wt[d][f] bf16
__global__ __launch_bounds__(256) void k_degwt(const float* __restrict__ adj,
                                               const float* __restrict__ W,
                                               float* __restrict__ rs,
                                               unsigned short* __restrict__ Wt) {
    if (blockIdx.x < 4096) {
        const int wave = threadIdx.x >> 6, lane = threadIdx.x & 63;
        const int row = blockIdx.x * 4 + wave;          // 0..B_*N_-1
        const float4* p = (const float4*)(adj + (size_t)row * N_);
        float s = 0.f;
#pragma unroll
        for (int j = 0; j < 8; ++j) {
            float4 v = p[j * 64 + lane];
            s += (v.x + v.y) + (v.z + v.w);
        }
#pragma unroll
        for (int m = 1; m < 64; m <<= 1) s += __shfl_xor(s, m, 64);
        if (lane == 0) rs[row] = (s > 0.f) ? (1.0f / sqrtf(s)) : 0.f;
    } else {
        // 8 blocks x 256 threads = 2048 chunks of 8 elements = 128*128
        int c = (blockIdx.x - 4096) * 256 + threadIdx.x;
        int d = c >> 4, f0 = (c & 15) * 8;
        union { bf16x8 v; unsigned short u[8]; } pk;
#pragma unroll
        for (int e = 0; e < 8; ++e) pk.u[e] = f2bf(W[(size_t)(f0 + e) * D_ + d]);
        *(bf16x8*)(Wt + (size_t)d * F_ + f0) = pk.v;
    }
}

// ---------------- Kernel 2: gt[b][d][m] = (X@W + bias)^T, bf16 (UNscaled) ----------------
// block: 64 rows (m) x 128 cols (d), 4 waves, MFMA 16x16x32 bf16
__global__ __launch_bounds__(256) void k_feat(const float* __restrict__ x,
                                              const unsigned short* __restrict__ Wt,
                                              const float* __restrict__ bias,
                                              unsigned short* __restrict__ gt) {
    __shared__ __align__(16) unsigned char sX[64 * 128 * 2];   // [row][f] bf16, 256B rows, swizzled
    __shared__ __align__(16) unsigned char sW[128 * 128 * 2];  // [d][f] bf16 (W^T), swizzled
    const int t = threadIdx.x;
    const int R0 = blockIdx.x * 64;

    // stage Wt via global_load_lds: linear LDS dest + inverse-swizzled global source
#pragma unroll
    for (int j = 0; j < 8; ++j) {
        int c = j * 256 + t;
        unsigned L = (unsigned)c * 16u;
        unsigned lg = L ^ (((L >> 8) & 7u) << 4);
        const unsigned char* src = (const unsigned char*)Wt + lg;
        __builtin_amdgcn_global_load_lds(
            (const __attribute__((address_space(1))) void*)src,
            (__attribute__((address_space(3))) void*)(sW + L), 16, 0, 0);
    }
    // stage X: 1024 x 16B chunks (8 bf16 each), 4 per thread, reg-staged (fp32->bf16)
#pragma unroll
    for (int j = 0; j < 4; ++j) {
        int c = j * 256 + t;
        int row = c >> 4, sub = c & 15;
        const float4* src = (const float4*)(x + (size_t)(R0 + row) * F_ + sub * 8);
        float4 v0 = src[0], v1 = src[1];
        union { bf16x8 v; unsigned short u[8]; } pk;
        pk.u[0] = f2bf(v0.x); pk.u[1] = f2bf(v0.y); pk.u[2] = f2bf(v0.z); pk.u[3] = f2bf(v0.w);
        pk.u[4] = f2bf(v1.x); pk.u[5] = f2bf(v1.y); pk.u[6] = f2bf(v1.z); pk.u[7] = f2bf(v1.w);
        unsigned byte = (unsigned)(row * 256 + sub * 16);
        byte ^= ((byte >> 8) & 7u) << 4;
        *(bf16x8*)(sX + byte) = pk.v;
    }
    __syncthreads();

    const int w = t >> 6, l = t & 63, lr = l & 15, lh = l >> 4;
    f32x4 acc[8];
#pragma unroll
    for (int j = 0; j < 8; ++j) acc[j] = (f32x4){0.f, 0.f, 0.f, 0.f};

#pragma unroll
    for (int ks = 0; ks < 4; ++ks) {
        int f0 = lh * 8 + ks * 32;
        unsigned abyte = (unsigned)((w * 16 + lr) * 256 + f0 * 2);
        abyte ^= ((abyte >> 8) & 7u) << 4;
        bf16x8 a = *(const bf16x8*)(sX + abyte);
#pragma unroll
        for (int j = 0; j < 8; ++j) {
            unsigned bbyte = (unsigned)((j * 16 + lr) * 256 + f0 * 2);
            bbyte ^= ((bbyte >> 8) & 7u) << 4;
            bf16x8 bb = *(const bf16x8*)(sW + bbyte);
            acc[j] = __builtin_amdgcn_mfma_f32_16x16x32_bf16(a, bb, acc[j], 0, 0, 0);
        }
    }

    // epilogue: add bias, store transposed bf16 (no rs scaling here)
#pragma unroll
    for (int j = 0; j < 8; ++j) {
        int d = j * 16 + lr;
        float bv = bias[d];
#pragma unroll
        for (int r = 0; r < 4; ++r) {
            int m = R0 + w * 16 + lh * 4 + r;
            float v = acc[j][r] + bv;
            int b = m >> 11, n = m & (N_ - 1);
            gt[((size_t)b * D_ + d) * N_ + n] = f2bf(v);
        }
    }
}

// ---------------- Kernel 3: out = relu(rs[n] * (adj*rs[m]) @ gt^T) ----------------
// block: 32 rows(n) x 128 cols(d), 8 waves (512 thr), BK=128, dbuf.
// wave w: rows (w>>2)*16, cols (w&3)*32.
__global__ __launch_bounds__(512) void k_gcn(const float* __restrict__ adj,
                                             const unsigned short* __restrict__ gt,
                                             const float* __restrict__ rs,
                                             float* __restrict__ out) {
    __shared__ __align__(16) unsigned char sA[2][32 * 128 * 2];    // adj*rs tile bf16, 256B rows, swz
    __shared__ __align__(16) unsigned char sB[2][128 * 128 * 2];   // gt tile [d][m] bf16, swz

    // XCD-aware swizzle: 512 blocks, 8 XCDs -> each XCD owns one batch
    unsigned bid = blockIdx.x;
    unsigned wg = (bid & 7u) * 64u + (bid >> 3);
    const int b = (int)(wg >> 6);
    const int nt = (int)(wg & 63u);
    const int R0 = nt * 32;

    const float* adjB = adj + (size_t)b * N_ * N_ + (size_t)R0 * N_;
    const unsigned short* gtB = gt + (size_t)b * D_ * N_;
    const float* rsB = rs + b * N_;

    const int t = threadIdx.x;
    const int w = t >> 6, l = t & 63, lr = l & 15, lh = l >> 4;
    const int wr = (w >> 2) * 16, wc = (w & 3) * 32;

    auto stage = [&](int bufidx, int k0) {
        // B: gt[d][k0..k0+127] -> sB, 2048 x 16B chunks via global_load_lds,
        // linear LDS dest + inverse-swizzled global source (both-sides rule)
        unsigned char* sBb = sB[bufidx];
#pragma unroll
        for (int i = 0; i < 4; ++i) {
            int c = i * 512 + t;
            unsigned L = (unsigned)c * 16u;
            unsigned lg = L ^ (((L >> 8) & 7u) << 4);
            int d = (int)(lg >> 8);
            int mloc = (int)(lg & 255u) >> 1;
            const unsigned short* g = gtB + (size_t)d * N_ + k0 + mloc;
            __builtin_amdgcn_global_load_lds(
                (const __attribute__((address_space(1))) void*)g,
                (__attribute__((address_space(3))) void*)(sBb + L), 16, 0, 0);
        }
        // A: adj fp32 * rs[m] -> bf16 reg-staged, 512 x 16B chunks, 1 per thread
        {
            int row = t >> 4, sub = t & 15;
            const float4* src = (const float4*)(adjB + (size_t)row * N_ + k0 + sub * 8);
            const float4* rsm = (const float4*)(rsB + k0 + sub * 8);
            float4 v0 = src[0], v1 = src[1];
            float4 r0 = rsm[0], r1 = rsm[1];
            union { bf16x8 v; unsigned short u[8]; } pk;
            pk.u[0] = f2bf(v0.x * r0.x); pk.u[1] = f2bf(v0.y * r0.y);
            pk.u[2] = f2bf(v0.z * r0.z); pk.u[3] = f2bf(v0.w * r0.w);
            pk.u[4] = f2bf(v1.x * r1.x); pk.u[5] = f2bf(v1.y * r1.y);
            pk.u[6] = f2bf(v1.z * r1.z); pk.u[7] = f2bf(v1.w * r1.w);
            unsigned byte = (unsigned)(row * 256 + sub * 16);
            byte ^= ((byte >> 8) & 7u) << 4;
            *(bf16x8*)(sA[bufidx] + byte) = pk.v;
        }
    };

    f32x4 acc[2];
    acc[0] = (f32x4){0.f, 0.f, 0.f, 0.f};
    acc[1] = (f32x4){0.f, 0.f, 0.f, 0.f};

    stage(0, 0);
    __syncthreads();

    const int NITER = N_ / 128;  // 16
    for (int it = 0; it < NITER; ++it) {
        int cur = it & 1;
        if (it + 1 < NITER) stage(cur ^ 1, (it + 1) * 128);

        const unsigned char* pA = sA[cur];
        const unsigned char* pB = sB[cur];
#pragma unroll
        for (int kk = 0; kk < 4; ++kk) {
            unsigned abyte = (unsigned)((wr + lr) * 256 + lh * 16 + kk * 64);
            abyte ^= ((abyte >> 8) & 7u) << 4;
            bf16x8 a = *(const bf16x8*)(pA + abyte);
#pragma unroll
            for (int jn = 0; jn < 2; ++jn) {
                int d = wc + jn * 16 + lr;
                unsigned bbyte = (unsigned)(d * 256 + lh * 16 + kk * 64);
                bbyte ^= ((bbyte >> 8) & 7u) << 4;
                bf16x8 bb = *(const bf16x8*)(pB + bbyte);
                acc[jn] = __builtin_amdgcn_mfma_f32_16x16x32_bf16(a, bb, acc[jn], 0, 0, 0);
            }
        }
        __syncthreads();
    }

    // epilogue: scale by rs[n], relu, store fp32
#pragma unroll
    for (int r = 0; r < 4; ++r) {
        int row = wr + lh * 4 + r;
        float rsn = rsB[R0 + row];
#pragma unroll
        for (int jn = 0; jn < 2; ++jn) {
            int d = wc + jn * 16 + lr;
            float v = acc[jn][r] * rsn;
            out[((size_t)(b * N_ + R0 + row)) * D_ + d] = fmaxf(v, 0.f);
        }
    }
}

extern "C" void kernel_launch(void* const* d_in, const int* in_sizes, int n_in,
                              void* d_out, int out_size, void* d_ws, size_t ws_size,
                              hipStream_t stream) {
    const float* inputs = (const float*)d_in[0];   // [B,N,F]
    const float* adj    = (const float*)d_in[1];   // [B,N,N]
    const float* Wk     = (const float*)d_in[2];   // [F,D]
    const float* Wb     = (const float*)d_in[3];   // [D]
    float* out = (float*)d_out;

    float* rs = (float*)d_ws;                                            // B*N fp32 = 64KB
    unsigned short* gt = (unsigned short*)((char*)d_ws + 65536);         // B*D*N bf16 = 4MB
    unsigned short* Wt = (unsigned short*)((char*)d_ws + 65536 + (size_t)B_ * D_ * N_ * 2); // 32KB

    k_degwt<<<4096 + 8, 256, 0, stream>>>(adj, Wk, rs, Wt);
    k_feat <<<(B_ * N_) / 64, 256, 0, stream>>>(inputs, Wt, Wb, gt);
    k_gcn  <<<B_ * (N_ / 32), 512, 0, stream>>>(adj, gt, rs, out);
}